// Round 2
// baseline (142.415 us; speedup 1.0000x reference)
//
#include <hip/hip_runtime.h>
#include <math.h>

// QASA layer: out = circuit(x @ W_in.T + b_in, q_weights) @ W_out.T + b_out
// 8 qubits -> 256 complex amps per row. Layout: 16 lanes per row, 4 rows per
// wave. State idx bits [7:4] = sublane t (lane&15), bits [3:0] = register r.
// Wire i acts on idx bit (7-i):
//   wires 0..3 -> sublane bits 3..0  (cross-lane, masks 8/4/2/1)
//   wires 4..7 -> register bits 3..0 (pure VALU)
// Cross-lane masks 1,2,8 use DPP (VALU pipe, full rate); mask 4 uses ds_swizzle.

template <int CTRL>
__device__ __forceinline__ float dppf(float v) {
    return __int_as_float(__builtin_amdgcn_update_dpp(
        0, __float_as_int(v), CTRL, 0xF, 0xF, true));
}

template <int MASK>
__device__ __forceinline__ float gsh(float v) {
    if constexpr (MASK == 1) return dppf<0xB1>(v);        // quad_perm [1,0,3,2]
    else if constexpr (MASK == 2) return dppf<0x4E>(v);   // quad_perm [2,3,0,1]
    else if constexpr (MASK == 8) return dppf<0x128>(v);  // row_ror:8 == xor 8 in 16
    else return __shfl_xor(v, MASK, 64);                  // mask 4 -> ds_swizzle
}

// butterfly sum over the 16-lane group (all lanes get the group total)
__device__ __forceinline__ float red16(float v) {
    v += dppf<0xB1>(v);
    v += dppf<0x4E>(v);
    v += __shfl_xor(v, 4, 64);
    v += dppf<0x128>(v);
    return v;
}

// RX(th1) then RZ(th2) on wire W. c1=cos(th1/2), s1=sin(th1/2), etc.
template <int W>
__device__ __forceinline__ void rot_gate(float re[16], float im[16],
                                         float c1, float s1, float c2, float s2,
                                         int t) {
    if constexpr (W < 4) {
        constexpr int MASK = 1 << (3 - W);
#pragma unroll
        for (int r = 0; r < 16; ++r) {
            float pre = gsh<MASK>(re[r]);
            float pim = gsh<MASK>(im[r]);
            re[r] = c1 * re[r] + s1 * pim;
            im[r] = c1 * im[r] - s1 * pre;
        }
        float ss = ((t >> (3 - W)) & 1) ? s2 : -s2;
#pragma unroll
        for (int r = 0; r < 16; ++r) {
            float nr = c2 * re[r] - ss * im[r];
            im[r] = c2 * im[r] + ss * re[r];
            re[r] = nr;
        }
    } else {
        constexpr int P = 1 << (7 - W);
#pragma unroll
        for (int r = 0; r < 16; ++r) {
            if ((r & P) == 0) {
                const int q = r | P;
                float ar = re[r], ai = im[r], br = re[q], bi = im[q];
                re[r] = c1 * ar + s1 * bi;
                im[r] = c1 * ai - s1 * br;
                re[q] = c1 * br + s1 * ai;
                im[q] = c1 * bi - s1 * ar;
            }
        }
#pragma unroll
        for (int r = 0; r < 16; ++r) {
            float ss = ((r >> (7 - W)) & 1) ? s2 : -s2;
            float nr = c2 * re[r] - ss * im[r];
            im[r] = c2 * im[r] + ss * re[r];
            re[r] = nr;
        }
    }
}

// CNOT, control = sublane bit CBIT, target = cross-lane mask MASK
template <int CBIT, int MASK>
__device__ __forceinline__ void cnot_lane(float re[16], float im[16], int t) {
    const bool ctrl = (t >> CBIT) & 1;
#pragma unroll
    for (int r = 0; r < 16; ++r) {
        float pr = gsh<MASK>(re[r]);
        float pi = gsh<MASK>(im[r]);
        re[r] = ctrl ? pr : re[r];
        im[r] = ctrl ? pi : im[r];
    }
}

// CNOT, control = sublane bit 0, target = register bit 3 (predicated reg swap)
__device__ __forceinline__ void cnot_43(float re[16], float im[16], int t) {
    const bool ctrl = t & 1;
#pragma unroll
    for (int r = 0; r < 8; ++r) {
        float ar = re[r], br = re[r + 8];
        re[r] = ctrl ? br : ar; re[r + 8] = ctrl ? ar : br;
        float ai = im[r], bi = im[r + 8];
        im[r] = ctrl ? bi : ai; im[r + 8] = ctrl ? ai : bi;
    }
}

// CNOT, control = register bit CB, target = register bit TB (free permutation)
template <int CB, int TB>
__device__ __forceinline__ void cnot_reg(float re[16], float im[16]) {
#pragma unroll
    for (int r = 0; r < 16; ++r) {
        if (((r >> CB) & 1) && !((r >> TB) & 1)) {
            const int q = r | (1 << TB);
            float tr = re[r]; re[r] = re[q]; re[q] = tr;
            float ti = im[r]; im[r] = im[q]; im[q] = ti;
        }
    }
}

__global__ void __launch_bounds__(256) qasa_kernel(
    const float* __restrict__ x, const float* __restrict__ W_in,
    const float* __restrict__ b_in, const float* __restrict__ qw,
    const float* __restrict__ W_out, const float* __restrict__ b_out,
    float* __restrict__ out)
{
    __shared__ float wc[64];
    __shared__ float ws[64];

    const int tid = threadIdx.x;
    const int lane = tid & 63;
    const int wave = tid >> 6;
    const int g = lane >> 4;       // row within wave
    const int t = lane & 15;       // sublane within 16-lane group
    const int rowbase = blockIdx.x * 16 + wave * 4;
    const size_t row = (size_t)(rowbase + g);

    // layer trig (wave-uniform), once per block
    if (tid < 64) {
        float sv, cv;
        __sincosf(0.5f * qw[tid], &sv, &cv);
        wc[tid] = cv; ws[tid] = sv;
    }
    __syncthreads();

    // ---- phase 1: angles = x[row] @ W_in.T + b_in (16 lanes per row) ----
    float ang[8];
    {
        float acc[8] = {0.f, 0.f, 0.f, 0.f, 0.f, 0.f, 0.f, 0.f};
        const float4* xr = (const float4*)(x + row * 1024);
        const float4* w4 = (const float4*)W_in;
#pragma unroll
        for (int k = 0; k < 16; ++k) {
            float4 xv = xr[t + 16 * k];
#pragma unroll
            for (int q = 0; q < 8; ++q) {
                float4 wv = w4[q * 256 + t + 16 * k];
                acc[q] += xv.x * wv.x + xv.y * wv.y + xv.z * wv.z + xv.w * wv.w;
            }
        }
#pragma unroll
        for (int q = 0; q < 8; ++q) ang[q] = red16(acc[q]) + b_in[q];
    }

    // ---- phase 2: circuit ----
    float re[16], im[16];
#pragma unroll
    for (int r = 0; r < 16; ++r) { re[r] = 0.f; im[r] = 0.f; }
    re[0] = (t == 0) ? 1.f : 0.f;

#define EMB(I) { float sv_, cv_; __sincosf(0.5f * ang[I], &sv_, &cv_); \
                 rot_gate<I>(re, im, cv_, sv_, cv_, sv_, t); }
    EMB(0) EMB(1) EMB(2) EMB(3) EMB(4) EMB(5) EMB(6) EMB(7)
#undef EMB

#pragma unroll 1
    for (int l = 0; l < 4; ++l) {
        const float* lc = wc + l * 16;
        const float* lsn = ws + l * 16;
#define LG(I) rot_gate<I>(re, im, lc[I], lsn[I], lc[8 + I], lsn[8 + I], t);
        LG(0) LG(1) LG(2) LG(3) LG(4) LG(5) LG(6) LG(7)
#undef LG
        // CNOT chain, control wire i -> target wire i+1
        cnot_lane<3, 4>(re, im, t);   // (7,6): ctrl t3, tgt mask4
        cnot_lane<2, 2>(re, im, t);   // (6,5)
        cnot_lane<1, 1>(re, im, t);   // (5,4)
        cnot_43(re, im, t);           // (4,3): ctrl t0, tgt reg bit3
        cnot_reg<3, 2>(re, im);       // (3,2)
        cnot_reg<2, 1>(re, im);       // (2,1)
        cnot_reg<1, 0>(re, im);       // (1,0)
    }

    // ---- phase 3: expvals <Z_i> ----
    float p[16];
#pragma unroll
    for (int r = 0; r < 16; ++r) p[r] = re[r] * re[r] + im[r] * im[r];
    float psum = 0.f;
#pragma unroll
    for (int r = 0; r < 16; ++r) psum += p[r];
    float sb0 = 0.f, sb1 = 0.f, sb2 = 0.f, sb3 = 0.f;
#pragma unroll
    for (int r = 0; r < 16; ++r) {
        sb0 += ((r >> 0) & 1) ? -p[r] : p[r];
        sb1 += ((r >> 1) & 1) ? -p[r] : p[r];
        sb2 += ((r >> 2) & 1) ? -p[r] : p[r];
        sb3 += ((r >> 3) & 1) ? -p[r] : p[r];
    }
    float ev[8];
    ev[0] = ((t >> 3) & 1) ? -psum : psum;
    ev[1] = ((t >> 2) & 1) ? -psum : psum;
    ev[2] = ((t >> 1) & 1) ? -psum : psum;
    ev[3] = ((t >> 0) & 1) ? -psum : psum;
    ev[4] = sb3; ev[5] = sb2; ev[6] = sb1; ev[7] = sb0;
#pragma unroll
    for (int q = 0; q < 8; ++q) ev[q] = red16(ev[q]);

    // ---- phase 4: out[row] = ev @ W_out.T + b_out (whole wave, 4 rows) ----
    // broadcast each group's ev to scalars
    float se[4][8];
#pragma unroll
    for (int g2 = 0; g2 < 4; ++g2)
#pragma unroll
        for (int q = 0; q < 8; ++q)
            se[g2][q] = __int_as_float(
                __builtin_amdgcn_readlane(__float_as_int(ev[q]), 16 * g2));

    const float4* wo4 = (const float4*)W_out;
    float* ob = out + (size_t)rowbase * 1024;
#pragma unroll
    for (int j = 0; j < 16; ++j) {
        const int col = lane + 64 * j;
        float4 a = wo4[2 * col];
        float4 b2 = wo4[2 * col + 1];
        float bias = b_out[col];
#pragma unroll
        for (int g2 = 0; g2 < 4; ++g2) {
            float o = bias
                + a.x * se[g2][0] + a.y * se[g2][1] + a.z * se[g2][2] + a.w * se[g2][3]
                + b2.x * se[g2][4] + b2.y * se[g2][5] + b2.z * se[g2][6] + b2.w * se[g2][7];
            ob[g2 * 1024 + col] = o;
        }
    }
}

extern "C" void kernel_launch(void* const* d_in, const int* in_sizes, int n_in,
                              void* d_out, int out_size, void* d_ws, size_t ws_size,
                              hipStream_t stream) {
    const float* x     = (const float*)d_in[0];
    const float* W_in  = (const float*)d_in[1];
    const float* b_in  = (const float*)d_in[2];
    const float* qw    = (const float*)d_in[3];
    const float* W_out = (const float*)d_in[4];
    const float* b_out = (const float*)d_in[5];
    float* outp = (float*)d_out;

    const int B = in_sizes[0] / 1024;   // 8192 rows
    const int grid = B / 16;            // 16 rows per 256-thread block
    qasa_kernel<<<grid, 256, 0, stream>>>(x, W_in, b_in, qw, W_out, b_out, outp);
}

// Round 3
// 128.404 us; speedup vs baseline: 1.1091x; 1.1091x over previous
//
#include <hip/hip_runtime.h>
#include <math.h>

// QASA layer: out = circuit(x @ W_in.T + b_in, q_weights) @ W_out.T + b_out
// 8 qubits -> 256 complex amps. ONE ROW PER WAVE (8192 waves = full TLP).
// State idx = lane*4 + r: idx bits [7:2] = lane bits [5:0], bits [1:0] = reg.
// Wire i acts on idx bit 7-i: wires 0..5 -> lane bits 5..0 (masks 32..1),
// wires 6,7 -> reg bits 1,0.
// Cross-lane: masks 1,2,8 via DPP (VALU pipe); 4,16 via ds_swizzle; 32 via shfl.

__device__ __forceinline__ int f2i(float v) { return __float_as_int(v); }
__device__ __forceinline__ float i2f(int v) { return __int_as_float(v); }

template <int CTRL>
__device__ __forceinline__ float dppf(float v) {
    return i2f(__builtin_amdgcn_update_dpp(0, f2i(v), CTRL, 0xF, 0xF, true));
}

template <int MASK>
__device__ __forceinline__ float gsh(float v) {
    if constexpr (MASK == 1)       return dppf<0xB1>(v);   // quad_perm [1,0,3,2]
    else if constexpr (MASK == 2)  return dppf<0x4E>(v);   // quad_perm [2,3,0,1]
    else if constexpr (MASK == 8)  return dppf<0x128>(v);  // row_ror:8 == xor8 in 16
    else if constexpr (MASK == 4)  return i2f(__builtin_amdgcn_ds_swizzle(f2i(v), 0x101F));
    else if constexpr (MASK == 16) return i2f(__builtin_amdgcn_ds_swizzle(f2i(v), 0x401F));
    else                           return __shfl_xor(v, 32, 64);
}

template <int L>
__device__ __forceinline__ float rdlane(float v) {
    return i2f(__builtin_amdgcn_readlane(f2i(v), L));
}

// RX(th1) then RZ(th2) on wire W (c1=cos(th1/2), s1=sin(th1/2), ...)
template <int W>
__device__ __forceinline__ void rot_gate(float re[4], float im[4],
                                         float c1, float s1, float c2, float s2,
                                         int lane) {
    if constexpr (W <= 5) {
        constexpr int MASK = 1 << (5 - W);
#pragma unroll
        for (int r = 0; r < 4; ++r) {
            float pre = gsh<MASK>(re[r]);
            float pim = gsh<MASK>(im[r]);
            re[r] = c1 * re[r] + s1 * pim;
            im[r] = c1 * im[r] - s1 * pre;
        }
        float ss = ((lane >> (5 - W)) & 1) ? s2 : -s2;
#pragma unroll
        for (int r = 0; r < 4; ++r) {
            float nr = c2 * re[r] - ss * im[r];
            im[r] = c2 * im[r] + ss * re[r];
            re[r] = nr;
        }
    } else {
        constexpr int P = (W == 6) ? 2 : 1;
        float nre[4], nim[4];
#pragma unroll
        for (int r = 0; r < 4; ++r) {
            nre[r] = c1 * re[r] + s1 * im[r ^ P];
            nim[r] = c1 * im[r] - s1 * re[r ^ P];
        }
#pragma unroll
        for (int r = 0; r < 4; ++r) {
            float ss = ((W == 6) ? ((r >> 1) & 1) : (r & 1)) ? s2 : -s2;
            re[r] = c2 * nre[r] - ss * nim[r];
            im[r] = c2 * nim[r] + ss * nre[r];
        }
    }
}

// CNOT: control = lane bit CB, target = cross mask M
template <int CB, int M>
__device__ __forceinline__ void cnot_lane(float re[4], float im[4], int lane) {
    const bool ctrl = (lane >> CB) & 1;
#pragma unroll
    for (int r = 0; r < 4; ++r) {
        float pr = gsh<M>(re[r]);
        float pi = gsh<M>(im[r]);
        re[r] = ctrl ? pr : re[r];
        im[r] = ctrl ? pi : im[r];
    }
}

// CNOT (wire5 -> wire6): ctrl lane bit0, swap reg pairs (0,2),(1,3)
__device__ __forceinline__ void cnot_56(float re[4], float im[4], int lane) {
    const bool ctrl = lane & 1;
#pragma unroll
    for (int r = 0; r < 2; ++r) {
        float a = re[r], b = re[r + 2];
        re[r] = ctrl ? b : a; re[r + 2] = ctrl ? a : b;
        float ai = im[r], bi = im[r + 2];
        im[r] = ctrl ? bi : ai; im[r + 2] = ctrl ? ai : bi;
    }
}

// CNOT (wire6 -> wire7): ctrl reg bit1, tgt reg bit0 -> swap regs 2,3 (free)
__device__ __forceinline__ void cnot_67(float re[4], float im[4]) {
    float t = re[2]; re[2] = re[3]; re[3] = t;
    t = im[2]; im[2] = im[3]; im[3] = t;
}

__global__ void __launch_bounds__(256, 4) qasa_kernel(
    const float* __restrict__ x, const float* __restrict__ W_in,
    const float* __restrict__ b_in, const float* __restrict__ qw,
    const float* __restrict__ W_out, const float* __restrict__ b_out,
    float* __restrict__ out)
{
    const int tid = threadIdx.x;
    const int lane = tid & 63;
    const size_t row = (size_t)blockIdx.x * 4 + (tid >> 6);

    // per-wave layer trig, lane-indexed in VGPRs (qw has exactly 64 entries)
    float vc, vs;
    __sincosf(0.5f * qw[lane], &vs, &vc);

    // ---- phase 1: angles = x[row] @ W_in.T + b_in ----
    float acc[8] = {0.f, 0.f, 0.f, 0.f, 0.f, 0.f, 0.f, 0.f};
    {
        const float4* xr = (const float4*)(x + row * 1024);
        const float4* w4 = (const float4*)W_in;
#pragma unroll
        for (int k = 0; k < 4; ++k) {
            float4 xv = xr[lane + 64 * k];
#pragma unroll
            for (int q = 0; q < 8; ++q) {
                float4 wv = w4[q * 256 + lane + 64 * k];
                acc[q] += xv.x * wv.x + xv.y * wv.y + xv.z * wv.z + xv.w * wv.w;
            }
        }
    }
    // partial-reduce each acc over lane bits {0,1,3} (DPP only)
#pragma unroll
    for (int q = 0; q < 8; ++q) {
        acc[q] += dppf<0xB1>(acc[q]);
        acc[q] += dppf<0x4E>(acc[q]);
        acc[q] += dppf<0x128>(acc[q]);
    }
    // transpose: lane picks acc[j], j = b0 | b1<<1 | b3<<2
    const int b0 = lane & 1, b1 = (lane >> 1) & 1, b3 = (lane >> 3) & 1;
    float t01 = b0 ? acc[1] : acc[0];
    float t23 = b0 ? acc[3] : acc[2];
    float t45 = b0 ? acc[5] : acc[4];
    float t67 = b0 ? acc[7] : acc[6];
    float ta = b1 ? t23 : t01;
    float tb = b1 ? t67 : t45;
    float A = b3 ? tb : ta;
    // finish: sum over lane bits {2,4,5}
    A += gsh<4>(A); A += gsh<16>(A); A += gsh<32>(A);
    A += b_in[b0 | (b1 << 1) | (b3 << 2)];
    float ec, es;
    __sincosf(0.5f * A, &es, &ec);  // lane L_q holds trig of angle q

    // ---- phase 2: circuit ----
    float re[4], im[4];
#pragma unroll
    for (int r = 0; r < 4; ++r) { re[r] = 0.f; im[r] = 0.f; }
    re[0] = (lane == 0) ? 1.f : 0.f;

    // embedding: RX(ang[q]);RZ(ang[q]) on wire q; trig lives in lane
    // L_q = (q&1) | ((q>>1)&1)<<1 | ((q>>2)&1)<<3
#define EMB(W_) { constexpr int L_ = ((W_) & 1) | ((((W_) >> 1) & 1) << 1) | ((((W_) >> 2) & 1) << 3); \
                  float c_ = rdlane<L_>(ec), s_ = rdlane<L_>(es); \
                  rot_gate<W_>(re, im, c_, s_, c_, s_, lane); }
    EMB(0) EMB(1) EMB(2) EMB(3) EMB(4) EMB(5) EMB(6) EMB(7)
#undef EMB

    // layers: qw[l][0][i] -> lane 16l+i (RX), qw[l][1][i] -> lane 16l+8+i (RZ)
#define LGATE(Lx, I_) rot_gate<I_>(re, im, \
        rdlane<16 * (Lx) + (I_)>(vc), rdlane<16 * (Lx) + (I_)>(vs), \
        rdlane<16 * (Lx) + 8 + (I_)>(vc), rdlane<16 * (Lx) + 8 + (I_)>(vs), lane);
#define LAYER(Lx) \
    LGATE(Lx, 0) LGATE(Lx, 1) LGATE(Lx, 2) LGATE(Lx, 3) \
    LGATE(Lx, 4) LGATE(Lx, 5) LGATE(Lx, 6) LGATE(Lx, 7) \
    cnot_lane<5, 16>(re, im, lane); \
    cnot_lane<4, 8>(re, im, lane);  \
    cnot_lane<3, 4>(re, im, lane);  \
    cnot_lane<2, 2>(re, im, lane);  \
    cnot_lane<1, 1>(re, im, lane);  \
    cnot_56(re, im, lane);          \
    cnot_67(re, im);
    LAYER(0) LAYER(1) LAYER(2) LAYER(3)
#undef LAYER
#undef LGATE

    // ---- phase 3: expvals ----
    float p0 = re[0] * re[0] + im[0] * im[0];
    float p1 = re[1] * re[1] + im[1] * im[1];
    float p2 = re[2] * re[2] + im[2] * im[2];
    float p3 = re[3] * re[3] + im[3] * im[3];
    float psum = (p0 + p1) + (p2 + p3);
    float s6 = (p0 + p1) - (p2 + p3);   // wire6: reg bit1
    float s7 = (p0 + p2) - (p1 + p3);   // wire7: reg bit0

    // Walsh-Hadamard butterfly on psum: lane 2^b ends with Z for lane-bit b
    float v = psum;
    { float u = dppf<0xB1>(v);  v = (lane & 1)  ? (u - v) : (v + u); }
    { float u = dppf<0x4E>(v);  v = (lane & 2)  ? (u - v) : (v + u); }
    { float u = dppf<0x128>(v); v = (lane & 8)  ? (u - v) : (v + u); }
    { float u = gsh<4>(v);      v = (lane & 4)  ? (u - v) : (v + u); }
    { float u = gsh<16>(v);     v = (lane & 16) ? (u - v) : (v + u); }
    { float u = gsh<32>(v);     v = (lane & 32) ? (u - v) : (v + u); }
    const float EV0 = rdlane<32>(v), EV1 = rdlane<16>(v), EV2 = rdlane<8>(v);
    const float EV3 = rdlane<4>(v),  EV4 = rdlane<2>(v),  EV5 = rdlane<1>(v);

    // s6/s7: partial DPP sums, interleave by bit0, finish with shared butterfly
    s6 += dppf<0xB1>(s6); s6 += dppf<0x4E>(s6); s6 += dppf<0x128>(s6);
    s7 += dppf<0xB1>(s7); s7 += dppf<0x4E>(s7); s7 += dppf<0x128>(s7);
    float w = (lane & 1) ? s7 : s6;
    w += gsh<4>(w); w += gsh<16>(w); w += gsh<32>(w);
    const float EV6 = rdlane<0>(w), EV7 = rdlane<1>(w);

    // ---- phase 4: out[row] = ev @ W_out.T + b_out (float4 cols per lane) ----
    const float4* wo = (const float4*)W_out;
    const float4* bo = (const float4*)b_out;
    float4* orow = (float4*)(out + row * 1024);
#pragma unroll
    for (int jj = 0; jj < 4; ++jj) {
        const int c4 = lane + 64 * jj;      // float4-col index; col0 = 4*c4
        float4 bias = bo[c4];
        float res[4];
#pragma unroll
        for (int c = 0; c < 4; ++c) {
            float4 wa = wo[2 * (4 * c4 + c)];
            float4 wb = wo[2 * (4 * c4 + c) + 1];
            res[c] = wa.x * EV0 + wa.y * EV1 + wa.z * EV2 + wa.w * EV3
                   + wb.x * EV4 + wb.y * EV5 + wb.z * EV6 + wb.w * EV7;
        }
        float4 o;
        o.x = bias.x + res[0]; o.y = bias.y + res[1];
        o.z = bias.z + res[2]; o.w = bias.w + res[3];
        orow[c4] = o;
    }
}

extern "C" void kernel_launch(void* const* d_in, const int* in_sizes, int n_in,
                              void* d_out, int out_size, void* d_ws, size_t ws_size,
                              hipStream_t stream) {
    const float* x     = (const float*)d_in[0];
    const float* W_in  = (const float*)d_in[1];
    const float* b_in  = (const float*)d_in[2];
    const float* qw    = (const float*)d_in[3];
    const float* W_out = (const float*)d_in[4];
    const float* b_out = (const float*)d_in[5];
    float* outp = (float*)d_out;

    const int B = in_sizes[0] / 1024;   // 8192 rows
    const int grid = B / 4;             // 4 rows (waves) per 256-thread block
    qasa_kernel<<<grid, 256, 0, stream>>>(x, W_in, b_in, qw, W_out, b_out, outp);
}